// Round 4
// baseline (204.172 us; speedup 1.0000x reference)
//
#include <hip/hip_runtime.h>
#include <hip/hip_bf16.h>

typedef unsigned short u16;
typedef unsigned long long u64;
typedef __attribute__((ext_vector_type(4))) float f32x4;
typedef __attribute__((ext_vector_type(8))) short bf16x8;

#define IN_F   4096
#define OUT_F  4096
#define BATCH  512

#define BM 64
#define BN 128
#define BK 64
#define NSTEPS (IN_F / BK)   // 64
#define DEPTH 4              // LDS ring buffers, prefetch distance 3

#define SLACK 1024           // bin capacity (mean 390, +32 sigma)

__device__ inline u16 f2bf(float f) {
    __hip_bfloat16 h = __float2bfloat16(f);   // RNE
    u16 u; __builtin_memcpy(&u, &h, 2); return u;
}

// Phase 1: bin nnz by output row. cursor[] pre-zeroed. Entry = (i<<12)|col.
// Hot-counter atomics (4096 L2-resident cursors) instead of 1.6M random-line
// atomics over 64MB (round1-3: pinned at ~67us = random 32B sector ceiling).
__global__ __launch_bounds__(256) void scatter_bin(const int* __restrict__ row,
                                                   const int* __restrict__ col,
                                                   int* __restrict__ cursor,
                                                   u64* __restrict__ bins, int nnz) {
    int t = blockIdx.x * 256 + threadIdx.x;
    int base = t * 4;
    if (base + 4 <= nnz) {
        int4 r = ((const int4*)row)[t];
        int4 c = ((const int4*)col)[t];
#pragma unroll
        for (int j = 0; j < 4; j++) {
            int rr = j == 0 ? r.x : j == 1 ? r.y : j == 2 ? r.z : r.w;
            int cc = j == 0 ? c.x : j == 1 ? c.y : j == 2 ? c.z : c.w;
            int i  = base + j;
            int off = atomicAdd(&cursor[rr], 1);
            if (off < SLACK) bins[(size_t)rr * SLACK + off] = ((u64)i << 12) | (u64)cc;
        }
    } else if (base < nnz) {
        for (int i = base; i < nnz; i++) {
            int rr = row[i], cc = col[i];
            int off = atomicAdd(&cursor[rr], 1);
            if (off < SLACK) bins[(size_t)rr * SLACK + off] = ((u64)i << 12) | (u64)cc;
        }
    }
}

// Phase 2: one block per W row. Last-write-wins via LDS atomicMax on global
// index, then build the dense bf16 row and stream it out.
__global__ __launch_bounds__(256) void build_w(const int* __restrict__ cursor,
                                               const u64* __restrict__ bins,
                                               const float* __restrict__ w,
                                               u16* __restrict__ Wbf) {
    __shared__ int auxr[IN_F];   // 16 KB
    const int row = blockIdx.x;
    const int tid = threadIdx.x;
#pragma unroll
    for (int j = 0; j < IN_F / 256; j++) auxr[tid + j * 256] = -1;
    __syncthreads();

    int cnt = cursor[row];
    if (cnt > SLACK) cnt = SLACK;
    const u64* seg = bins + (size_t)row * SLACK;
    for (int k = tid; k < cnt; k += 256) {
        u64 e = seg[k];
        atomicMax(&auxr[(int)(e & 4095)], (int)(e >> 12));
    }
    __syncthreads();

    int base = tid * 16;
    ushort4 o[4];
#pragma unroll
    for (int j = 0; j < 16; j++) {
        int a = auxr[base + j];
        ((u16*)o)[j] = a >= 0 ? f2bf(w[a]) : (u16)0;
    }
    uint4* dst = (uint4*)(Wbf + (size_t)row * IN_F + base);
    dst[0] = ((const uint4*)o)[0];
    dst[1] = ((const uint4*)o)[1];
}

__global__ __launch_bounds__(256) void conv_x(const float* __restrict__ x,
                                              u16* __restrict__ xbf) {
    int i = blockIdx.x * 256 + threadIdx.x;   // handles 4 elements
    float4 v = ((const float4*)x)[i];
    ushort4 o;
    o.x = f2bf(v.x); o.y = f2bf(v.y); o.z = f2bf(v.z); o.w = f2bf(v.w);
    ((ushort4*)xbf)[i] = o;
}

// C[m][n] = sum_k A[m][k]*B[n][k] + bias[n].  (unchanged from round 3)
__global__ __launch_bounds__(256) void gemm_bias(const u16* __restrict__ A,
                                                 const u16* __restrict__ B,
                                                 const float* __restrict__ bias,
                                                 float* __restrict__ C) {
    __shared__ u16 As[DEPTH][BM * BK];   // 4 x 8 KB
    __shared__ u16 Bs[DEPTH][BN * BK];   // 4 x 16 KB  => 96 KB total
    const int L  = blockIdx.x;
    const int m0 = (L >> 5) * BM;        // 8 M-blocks
    const int n0 = (L & 31) * BN;        // 32 N-blocks; L%8==n%8 -> same-n blocks share an XCD
    const int tid  = threadIdx.x;
    const int lane = tid & 63;
    const int wave = tid >> 6;
    const int wm = wave >> 1, wn = wave & 1;   // 2x2 waves, wave tile 32x64
    const int r15 = lane & 15, khi = lane >> 4;

    // Pre-swizzled per-thread staging sources. LDS slot (row, lblk) holds
    // global 16B block gblk = lblk ^ (row&7).  (o is 16B-aligned)
    const u16* srcA[2]; int dstA[2];
    const u16* srcB[4]; int dstB[4];
#pragma unroll
    for (int it = 0; it < 2; it++) {
        int o = tid * 16 + it * 4096;
        int rr = o >> 7, lblk = (o >> 4) & 7;
        srcA[it] = A + (size_t)(m0 + rr) * IN_F + ((lblk ^ (rr & 7)) << 3);
        dstA[it] = o >> 1;
    }
#pragma unroll
    for (int it = 0; it < 4; it++) {
        int o = tid * 16 + it * 4096;
        int rr = o >> 7, lblk = (o >> 4) & 7;
        srcB[it] = B + (size_t)(n0 + rr) * IN_F + ((lblk ^ (rr & 7)) << 3);
        dstB[it] = o >> 1;
    }

#define STAGE(slot, kt)                                                              \
    do {                                                                             \
        _Pragma("unroll")                                                            \
        for (int it = 0; it < 2; it++)                                               \
            __builtin_amdgcn_global_load_lds(                                        \
                (const __attribute__((address_space(1))) void*)(srcA[it] + (kt)),    \
                (__attribute__((address_space(3))) void*)(&As[slot][dstA[it]]),      \
                16, 0, 0);                                                           \
        _Pragma("unroll")                                                            \
        for (int it = 0; it < 4; it++)                                               \
            __builtin_amdgcn_global_load_lds(                                        \
                (const __attribute__((address_space(1))) void*)(srcB[it] + (kt)),    \
                (__attribute__((address_space(3))) void*)(&Bs[slot][dstB[it]]),      \
                16, 0, 0);                                                           \
    } while (0)

    f32x4 acc[2][4];
#pragma unroll
    for (int mi = 0; mi < 2; mi++)
#pragma unroll
        for (int nj = 0; nj < 4; nj++) acc[mi][nj] = (f32x4){0.f, 0.f, 0.f, 0.f};

    STAGE(0, 0); STAGE(1, BK); STAGE(2, 2 * BK);   // 18 loads/wave outstanding

    for (int t = 0; t < NSTEPS; ++t) {
        if (t < NSTEPS - 2)       asm volatile("s_waitcnt vmcnt(12)" ::: "memory");
        else if (t == NSTEPS - 2) asm volatile("s_waitcnt vmcnt(6)"  ::: "memory");
        else                      asm volatile("s_waitcnt vmcnt(0)"  ::: "memory");
        __builtin_amdgcn_s_barrier();
        __builtin_amdgcn_sched_barrier(0);
        if (t + 3 < NSTEPS) STAGE((t + 3) & 3, (t + 3) * BK);

        const char* as = (const char*)&As[t & 3][0];
        const char* bs = (const char*)&Bs[t & 3][0];
#pragma unroll
        for (int ks = 0; ks < 2; ks++) {
            bf16x8 a[2], b[4];
#pragma unroll
            for (int mi = 0; mi < 2; mi++) {
                int rowi = wm * 32 + mi * 16 + r15;
                a[mi] = *(const bf16x8*)(as + rowi * 128 + (((ks * 4 + khi) ^ (rowi & 7)) << 4));
            }
#pragma unroll
            for (int nj = 0; nj < 4; nj++) {
                int rowi = wn * 64 + nj * 16 + r15;
                b[nj] = *(const bf16x8*)(bs + rowi * 128 + (((ks * 4 + khi) ^ (rowi & 7)) << 4));
            }
#pragma unroll
            for (int mi = 0; mi < 2; mi++)
#pragma unroll
                for (int nj = 0; nj < 4; nj++)
                    acc[mi][nj] = __builtin_amdgcn_mfma_f32_16x16x32_bf16(a[mi], b[nj], acc[mi][nj], 0, 0, 0);
        }
    }
#undef STAGE

    // epilogue: D layout col=lane&15, row=(lane>>4)*4+j; bias fused
#pragma unroll
    for (int nj = 0; nj < 4; nj++) {
        int colg = n0 + wn * 64 + nj * 16 + r15;
        float bv = bias[colg];
#pragma unroll
        for (int mi = 0; mi < 2; mi++) {
#pragma unroll
            for (int j = 0; j < 4; j++) {
                int rowg = m0 + wm * 32 + mi * 16 + khi * 4 + j;
                C[(size_t)rowg * OUT_F + colg] = acc[mi][nj][j] + bv;
            }
        }
    }
}

extern "C" void kernel_launch(void* const* d_in, const int* in_sizes, int n_in,
                              void* d_out, int out_size, void* d_ws, size_t ws_size,
                              hipStream_t stream) {
    const float* x    = (const float*)d_in[0];
    const float* w1d  = (const float*)d_in[1];
    const float* bias = (const float*)d_in[2];
    const int*   row  = (const int*)d_in[3];
    const int*   col  = (const int*)d_in[4];
    const int nnz = in_sizes[1];

    char* ws      = (char*)d_ws;
    u64*  bins    = (u64*)ws;                             // 32 MB [0,32)
    int*  cursor  = (int*)(ws + ((size_t)32 << 20));      // 16 KB
    u16*  Wbf     = (u16*)(ws + ((size_t)64 << 20));      // 32 MB [64,96)
    u16*  xbf     = (u16*)(ws + ((size_t)96 << 20));      // 4 MB  [96,100)
    float* y      = (float*)d_out;

    conv_x<<<(BATCH * IN_F / 4) / 256, 256, 0, stream>>>(x, xbf);
    hipMemsetAsync(cursor, 0, OUT_F * sizeof(int), stream);
    int bthreads = (nnz + 3) / 4;
    scatter_bin<<<(bthreads + 255) / 256, 256, 0, stream>>>(row, col, cursor, bins, nnz);
    build_w<<<OUT_F, 256, 0, stream>>>(cursor, bins, w1d, Wbf);
    gemm_bias<<<8 * 32, 256, 0, stream>>>(xbf, Wbf, bias, y);
}

// Round 5
// 144.158 us; speedup vs baseline: 1.4163x; 1.4163x over previous
//
#include <hip/hip_runtime.h>
#include <hip/hip_bf16.h>

typedef unsigned short u16;
typedef unsigned long long u64;
typedef __attribute__((ext_vector_type(4))) float f32x4;
typedef __attribute__((ext_vector_type(8))) short bf16x8;

#define IN_F   4096
#define OUT_F  4096
#define BATCH  512

#define BM 64
#define BN 64
#define BK 64
#define NSTEPS (IN_F / BK)   // 64
#define DEPTH 4              // LDS ring, prefetch distance 3

#define NXCD  8
#define SLACK 224            // per (row,xcd) bin capacity; mean 49, +25 sigma

__device__ inline u16 f2bf(float f) {
    __hip_bfloat16 h = __float2bfloat16(f);   // RNE
    u16 u; __builtin_memcpy(&u, &h, 2); return u;
}

// Phase 1: bin nnz by (output row, MY OWN XCD). Round-4 lesson: shared bins
// appended from 8 XCDs bounce lines between non-coherent L2s -> 91MB of HBM
// sector writes. Private per-XCD bins keep cursor+data lines in ONE L2.
// Wrong XCC_ID would only hurt locality, never correctness (build_w merges all).
__global__ __launch_bounds__(256) void scatter_bin(const int* __restrict__ row,
                                                   const int* __restrict__ col,
                                                   int* __restrict__ cursor,
                                                   u64* __restrict__ bins, int nnz) {
    // hwreg(HW_REG_XCC_ID=20, offset 0, width 4): imm = id | (width-1)<<11
    int xcd = __builtin_amdgcn_s_getreg(20 | (3 << 11)) & (NXCD - 1);
    int* mycur = cursor + (xcd << 12);
    u64* mybin = bins + ((size_t)xcd << 12) * SLACK;

    int t = blockIdx.x * 256 + threadIdx.x;
    int base = t * 4;
    if (base + 4 <= nnz) {
        int4 r = ((const int4*)row)[t];
        int4 c = ((const int4*)col)[t];
#pragma unroll
        for (int j = 0; j < 4; j++) {
            int rr = j == 0 ? r.x : j == 1 ? r.y : j == 2 ? r.z : r.w;
            int cc = j == 0 ? c.x : j == 1 ? c.y : j == 2 ? c.z : c.w;
            int i  = base + j;
            int off = atomicAdd(&mycur[rr], 1);
            if (off < SLACK) mybin[(size_t)rr * SLACK + off] = ((u64)i << 12) | (u64)cc;
        }
    } else if (base < nnz) {
        int e = nnz < base + 4 ? nnz : base + 4;
        for (int i = base; i < e; i++) {
            int rr = row[i], cc = col[i];
            int off = atomicAdd(&mycur[rr], 1);
            if (off < SLACK) mybin[(size_t)rr * SLACK + off] = ((u64)i << 12) | (u64)cc;
        }
    }
}

// Phase 2: one block per W row. Merge the 8 per-XCD segments; last-write-wins
// via LDS atomicMax on global index; stream out the dense bf16 row.
__global__ __launch_bounds__(256) void build_w(const int* __restrict__ cursor,
                                               const u64* __restrict__ bins,
                                               const float* __restrict__ w,
                                               u16* __restrict__ Wbf) {
    __shared__ int auxr[IN_F];   // 16 KB
    const int row = blockIdx.x;
    const int tid = threadIdx.x;
#pragma unroll
    for (int j = 0; j < IN_F / 256; j++) auxr[tid + j * 256] = -1;
    __syncthreads();

#pragma unroll
    for (int xcd = 0; xcd < NXCD; xcd++) {
        int cnt = cursor[(xcd << 12) + row];
        if (cnt > SLACK) cnt = SLACK;
        const u64* seg = bins + ((size_t)((xcd << 12) + row)) * SLACK;
        for (int k = tid; k < cnt; k += 256) {
            u64 e = seg[k];
            atomicMax(&auxr[(int)(e & 4095)], (int)(e >> 12));
        }
    }
    __syncthreads();

    int base = tid * 16;
    ushort4 o[4];
#pragma unroll
    for (int j = 0; j < 16; j++) {
        int a = auxr[base + j];
        ((u16*)o)[j] = a >= 0 ? f2bf(w[a]) : (u16)0;
    }
    uint4* dst = (uint4*)(Wbf + (size_t)row * IN_F + base);
    dst[0] = ((const uint4*)o)[0];
    dst[1] = ((const uint4*)o)[1];
}

__global__ __launch_bounds__(256) void conv_x(const float* __restrict__ x,
                                              u16* __restrict__ xbf) {
    int i = blockIdx.x * 256 + threadIdx.x;   // handles 4 elements
    float4 v = ((const float4*)x)[i];
    ushort4 o;
    o.x = f2bf(v.x); o.y = f2bf(v.y); o.z = f2bf(v.z); o.w = f2bf(v.w);
    ((ushort4*)xbf)[i] = o;
}

// C[m][n] = sum_k A[m][k]*B[n][k] + bias[n].
// 64x64 tile, grid 512 = 2 blocks/CU (TLP regime fix vs round 3's 1/CU),
// DEPTH=4 ring (64KB LDS), counted vmcnt, source-side XOR swizzle (verified).
__global__ __launch_bounds__(256) void gemm_bias(const u16* __restrict__ A,
                                                 const u16* __restrict__ B,
                                                 const float* __restrict__ bias,
                                                 float* __restrict__ C) {
    __shared__ u16 As[DEPTH][BM * BK];   // 4 x 8 KB
    __shared__ u16 Bs[DEPTH][BN * BK];   // 4 x 8 KB  => 64 KB
    const int L  = blockIdx.x;
    const int g  = L >> 3, xx = L & 7;
    const int m0 = (g >> 3) * BM;                 // 8 M-blocks
    const int n0 = (xx + ((g & 7) << 3)) * BN;    // 64 N-panels; n%8==L%8 -> panel sharers on one XCD
    const int tid  = threadIdx.x;
    const int lane = tid & 63;
    const int wave = tid >> 6;
    const int wm = wave >> 1, wn = wave & 1;      // 2x2 waves, wave tile 32x32
    const int r15 = lane & 15, khi = lane >> 4;

    // LDS slot s of row r holds global 16B-block s ^ (r&7)  (o is 16B-aligned)
    const u16* srcA[2]; const u16* srcB[2]; int dstO[2];
#pragma unroll
    for (int it = 0; it < 2; it++) {
        int o = tid * 16 + it * 4096;
        int rr = o >> 7, lblk = (o >> 4) & 7;
        srcA[it] = A + (size_t)(m0 + rr) * IN_F + ((lblk ^ (rr & 7)) << 3);
        srcB[it] = B + (size_t)(n0 + rr) * IN_F + ((lblk ^ (rr & 7)) << 3);
        dstO[it] = o >> 1;
    }

#define STAGE(slot, kt)                                                              \
    do {                                                                             \
        _Pragma("unroll")                                                            \
        for (int it = 0; it < 2; it++)                                               \
            __builtin_amdgcn_global_load_lds(                                        \
                (const __attribute__((address_space(1))) void*)(srcA[it] + (kt)),    \
                (__attribute__((address_space(3))) void*)(&As[slot][dstO[it]]),      \
                16, 0, 0);                                                           \
        _Pragma("unroll")                                                            \
        for (int it = 0; it < 2; it++)                                               \
            __builtin_amdgcn_global_load_lds(                                        \
                (const __attribute__((address_space(1))) void*)(srcB[it] + (kt)),    \
                (__attribute__((address_space(3))) void*)(&Bs[slot][dstO[it]]),      \
                16, 0, 0);                                                           \
    } while (0)

    f32x4 acc[2][2];
#pragma unroll
    for (int mi = 0; mi < 2; mi++)
#pragma unroll
        for (int nj = 0; nj < 2; nj++) acc[mi][nj] = (f32x4){0.f, 0.f, 0.f, 0.f};

    STAGE(0, 0); STAGE(1, BK); STAGE(2, 2 * BK);   // 12 loads outstanding

    for (int t = 0; t < NSTEPS; ++t) {
        if (t < NSTEPS - 2)       asm volatile("s_waitcnt vmcnt(8)" ::: "memory");
        else if (t == NSTEPS - 2) asm volatile("s_waitcnt vmcnt(4)" ::: "memory");
        else                      asm volatile("s_waitcnt vmcnt(0)" ::: "memory");
        __builtin_amdgcn_s_barrier();
        __builtin_amdgcn_sched_barrier(0);
        if (t + 3 < NSTEPS) STAGE((t + 3) & 3, (t + 3) * BK);

        const char* as = (const char*)&As[t & 3][0];
        const char* bs = (const char*)&Bs[t & 3][0];
#pragma unroll
        for (int ks = 0; ks < 2; ks++) {
            bf16x8 a[2], b[2];
#pragma unroll
            for (int mi = 0; mi < 2; mi++) {
                int rowi = wm * 32 + mi * 16 + r15;
                a[mi] = *(const bf16x8*)(as + rowi * 128 + (((ks * 4 + khi) ^ (rowi & 7)) << 4));
            }
#pragma unroll
            for (int nj = 0; nj < 2; nj++) {
                int rowi = wn * 32 + nj * 16 + r15;
                b[nj] = *(const bf16x8*)(bs + rowi * 128 + (((ks * 4 + khi) ^ (rowi & 7)) << 4));
            }
#pragma unroll
            for (int mi = 0; mi < 2; mi++)
#pragma unroll
                for (int nj = 0; nj < 2; nj++)
                    acc[mi][nj] = __builtin_amdgcn_mfma_f32_16x16x32_bf16(a[mi], b[nj], acc[mi][nj], 0, 0, 0);
        }
    }
#undef STAGE

    // epilogue: D layout col=lane&15, row=(lane>>4)*4+j; bias fused
#pragma unroll
    for (int nj = 0; nj < 2; nj++) {
        int colg = n0 + wn * 32 + nj * 16 + r15;
        float bv = bias[colg];
#pragma unroll
        for (int mi = 0; mi < 2; mi++) {
#pragma unroll
            for (int j = 0; j < 4; j++) {
                int rowg = m0 + wm * 32 + mi * 16 + khi * 4 + j;
                C[(size_t)rowg * OUT_F + colg] = acc[mi][nj][j] + bv;
            }
        }
    }
}

extern "C" void kernel_launch(void* const* d_in, const int* in_sizes, int n_in,
                              void* d_out, int out_size, void* d_ws, size_t ws_size,
                              hipStream_t stream) {
    const float* x    = (const float*)d_in[0];
    const float* w1d  = (const float*)d_in[1];
    const float* bias = (const float*)d_in[2];
    const int*   row  = (const int*)d_in[3];
    const int*   col  = (const int*)d_in[4];
    const int nnz = in_sizes[1];

    char* ws      = (char*)d_ws;
    u64*  bins    = (u64*)ws;                             // 8*4096*224*8 = 58.7 MB
    int*  cursor  = (int*)(ws + ((size_t)60 << 20));      // 128 KB
    u16*  Wbf     = (u16*)(ws + ((size_t)64 << 20));      // 32 MB
    u16*  xbf     = (u16*)(ws + ((size_t)96 << 20));      // 4 MB
    float* y      = (float*)d_out;

    conv_x<<<(BATCH * IN_F / 4) / 256, 256, 0, stream>>>(x, xbf);
    hipMemsetAsync(cursor, 0, NXCD * OUT_F * sizeof(int), stream);
    int bthreads = (nnz + 3) / 4;
    scatter_bin<<<(bthreads + 255) / 256, 256, 0, stream>>>(row, col, cursor, bins, nnz);
    build_w<<<OUT_F, 256, 0, stream>>>(cursor, bins, w1d, Wbf);
    gemm_bias<<<8 * 64, 256, 0, stream>>>(xbf, Wbf, bias, y);
}